// Round 4
// baseline (68.391 us; speedup 1.0000x reference)
//
#include <hip/hip_runtime.h>
#include <math.h>
#include <limits.h>

// Problem constants (fixed by reference setup_inputs)
constexpr int N = 8;
constexpr int H = 256;
constexpr int W = 256;
constexpr int NPIX = N * H * W;            // 524288
constexpr float FEPS = 1e-6f;
constexpr int   RSENT = 20000;             // row-empty sentinel: RSENT^2=4e8 >> legit max 130050
constexpr int   EMPTY_THRESH = 300000000;  // > legit max 130050, < RSENT^2
constexpr int   NROW = N * H;              // 2048 per-row partial slots (layout == old kernel)
constexpr int   RPB  = 4;                  // output rows per block
constexpr int   NBLK = NROW / RPB;         // 512 fused blocks
constexpr int   NSLOT = RPB + 6;           // 10 window row slots: qy in [py0-3, py0+RPB+2]
constexpr int   BIGD = 1 << 20;
constexpr unsigned long long MAGIC = 0x9E3779B97F4A7C15ull; // halves differ -> no uniform
                                                            // poison pattern can match

// ws layout:
//   float parts[5][NROW]  : q=0: p*t, 1: p, 2: t, 3: phi*p, 4: focal   (40 KB)
//   u64   flags[NBLK]     : per-block completion magic                  (4 KB)

// ---- nearest-set-bit distances from a 256-bit row mask ----
// Row pixel i <-> bit (i&63) of word (i>>6). Masks are wave-uniform (from __ballot).
// Computes r[k] = distance from pixel p = 64k+lane to nearest set bit (RSENT if none).
__device__ __forceinline__ void mask_dists(
    const unsigned long long m0, const unsigned long long m1,
    const unsigned long long m2, const unsigned long long m3,
    const int lane, int r[4])
{
    // right-chains: dJ = dist from bit0 of word J to nearest set bit in words J..3
    const int f1 = __ffsll((long long)m1), f2 = __ffsll((long long)m2), f3 = __ffsll((long long)m3);
    const int d3 = f3 ? f3 - 1 : BIGD;
    const int d2 = f2 ? f2 - 1 : 64 + d3;
    const int d1 = f1 ? f1 - 1 : 64 + d2;
    // left-chains: eJ = dist from bit63 of word J to nearest set bit in words J..0
    const int c0 = __clzll((long long)m0), c1 = __clzll((long long)m1), c2 = __clzll((long long)m2);
    const int e0 = (c0 < 64) ? c0 : BIGD;
    const int e1 = (c1 < 64) ? c1 : 64 + e0;
    const int e2 = (c2 < 64) ? c2 : 64 + e1;

    const unsigned long long mw[4] = {m0, m1, m2, m3};
    const int dnx[4] = {d1, d2, d3, BIGD};
    const int epv[4] = {BIGD, e0, e1, e2};
    #pragma unroll
    for (int k = 0; k < 4; ++k) {
        const unsigned long long x = mw[k] >> lane;          // bit0 = self
        const int fx = __ffsll((long long)x);
        const int dR = fx ? fx - 1 : (64 - lane) + dnx[k];
        const unsigned long long y = mw[k] << (63 - lane);   // bit63 = self
        const int cy = __clzll((long long)y);
        const int dL = (cy < 64) ? cy : (lane + 1) + epv[k];
        int rr = min(dL, dR);
        if (rr > 255) rr = RSENT;
        r[k] = rr;
    }
}

// ---- single-pixel distance for pixel (word=wid, bit=lane) from uniform masks ----
__device__ __forceinline__ int mask_dist_one(
    const unsigned long long m0, const unsigned long long m1,
    const unsigned long long m2, const unsigned long long m3,
    const int wid, const int lane)
{
    const int f1 = __ffsll((long long)m1), f2 = __ffsll((long long)m2), f3 = __ffsll((long long)m3);
    const int d3 = f3 ? f3 - 1 : BIGD;
    const int d2 = f2 ? f2 - 1 : 64 + d3;
    const int d1c = f1 ? f1 - 1 : 64 + d2;
    const int c0 = __clzll((long long)m0), c1 = __clzll((long long)m1), c2 = __clzll((long long)m2);
    const int e0 = (c0 < 64) ? c0 : BIGD;
    const int e1 = (c1 < 64) ? c1 : 64 + e0;
    const int e2 = (c2 < 64) ? c2 : 64 + e1;
    const unsigned long long mw = (wid == 0) ? m0 : (wid == 1) ? m1 : (wid == 2) ? m2 : m3;
    const int dnx = (wid == 0) ? d1c : (wid == 1) ? d2 : (wid == 2) ? d3 : BIGD;
    const int epv = (wid == 0) ? BIGD : (wid == 1) ? e0 : (wid == 2) ? e1 : e2;
    const unsigned long long xx = mw >> lane;
    const int fx = __ffsll((long long)xx);
    const int dR = fx ? fx - 1 : (64 - lane) + dnx;
    const unsigned long long yy = mw << (63 - lane);
    const int cy = __clzll((long long)yy);
    const int dL = (cy < 64) ? cy : (lane + 1) + epv;
    int rr = min(dL, dR); if (rr > 255) rr = RSENT;
    return rr;
}

__global__ __launch_bounds__(256, 4) void fused_kernel(
    const float* __restrict__ pred, const float* __restrict__ tgt,
    float* __restrict__ parts, unsigned long long* __restrict__ flags,
    float* __restrict__ out)
{
    const int blk  = blockIdx.x;            // n*64 + (py0>>2)
    const int n    = blk >> 6;
    const int py0  = (blk & 63) << 2;
    const int px   = threadIdx.x;
    const int lane = px & 63;
    const int wid  = px >> 6;

    __shared__ unsigned int rows[NSLOT][W]; // packed rf | rb<<16, slot s <-> qy = py0-3+s
    __shared__ float smem[RPB][20];
    __shared__ float smf[8];
    __shared__ float sratio[8];

    const float* __restrict__ timg = tgt  + (size_t)n * (H * W);
    const float* __restrict__ pimg = pred + (size_t)n * (H * W);

    // ---- window row-scans: wave w computes slots w, w+4, w+8 entirely in-wave ----
    #pragma unroll
    for (int sh = 0; sh < 3; ++sh) {
        const int s  = wid + (sh << 2);
        const int qy = py0 - 3 + s;
        if (s < NSLOT && qy >= 0 && qy < H) { // wave-uniform
            const float a0 = timg[qy * W + lane];
            const float a1 = timg[qy * W + 64 + lane];
            const float a2 = timg[qy * W + 128 + lane];
            const float a3 = timg[qy * W + 192 + lane];
            const unsigned long long m0 = __ballot(a0 > 0.5f);
            const unsigned long long m1 = __ballot(a1 > 0.5f);
            const unsigned long long m2 = __ballot(a2 > 0.5f);
            const unsigned long long m3 = __ballot(a3 > 0.5f);
            int rf[4], rb[4];
            mask_dists(m0, m1, m2, m3, lane, rf);
            mask_dists(~m0, ~m1, ~m2, ~m3, lane, rb);
            #pragma unroll
            for (int k = 0; k < 4; ++k)
                rows[s][(k << 6) + lane] = (unsigned)rf[k] | ((unsigned)rb[k] << 16);
        }
    }

    // hot loads for the loss phase (issue early, overlap with barrier + window min)
    float xv[RPB], tv[RPB];
    #pragma unroll
    for (int r = 0; r < RPB; ++r) {
        xv[r] = pimg[(py0 + r) * W + px];
        tv[r] = timg[(py0 + r) * W + px];
    }

    __syncthreads();

    // ---- windowed column pass for all RPB output rows from LDS ----
    int bf[RPB], bb[RPB];
    #pragma unroll
    for (int r = 0; r < RPB; ++r) { bf[r] = INT_MAX; bb[r] = INT_MAX; }
    #pragma unroll
    for (int s = 0; s < NSLOT; ++s) {
        const int qy = py0 - 3 + s;
        if (qy >= 0 && qy < H) {            // wave-uniform
            const unsigned v = rows[s][px];
            const int rfv = (int)(v & 0xffffu);
            const int rbv = (int)(v >> 16);
            const int rf2 = rfv * rfv, rb2 = rbv * rbv;
            #pragma unroll
            for (int r = 0; r < RPB; ++r) {
                const int d = s - 3 - r;
                bf[r] = min(bf[r], rf2 + d * d);
                bb[r] = min(bb[r], rb2 + d * d);
            }
        }
    }

    // ---- rare exact fallback: extend outward, recomputing rows on demand ----
    // Each wave loads the full row, ballots (identical masks), and every thread
    // computes its own pixel's distance: word index = wid (wave-uniform), bit = lane.
    for (int dir = 0; dir < 2; ++dir) {
        const int qy_start = dir ? py0 + RPB + 3 : py0 - 4;
        const int qy_step  = dir ? 1 : -1;
        for (int qy = qy_start; qy >= 0 && qy < H; qy += qy_step) {
            int ds[RPB];
            bool improve = false;
            #pragma unroll
            for (int r = 0; r < RPB; ++r) {
                const int d = dir ? (qy - py0 - r) : (py0 + r - qy);
                ds[r] = d * d;
                improve = improve | (ds[r] < bf[r]) | (ds[r] < bb[r]);
            }
            if (!__any(improve)) break;
            const float a0 = timg[qy * W + lane];
            const float a1 = timg[qy * W + 64 + lane];
            const float a2 = timg[qy * W + 128 + lane];
            const float a3 = timg[qy * W + 192 + lane];
            const unsigned long long m0 = __ballot(a0 > 0.5f);
            const unsigned long long m1 = __ballot(a1 > 0.5f);
            const unsigned long long m2 = __ballot(a2 > 0.5f);
            const unsigned long long m3 = __ballot(a3 > 0.5f);
            const int rfv = mask_dist_one(m0, m1, m2, m3, wid, lane);
            const int rbv = mask_dist_one(~m0, ~m1, ~m2, ~m3, wid, lane);
            const int rf2 = rfv * rfv, rb2 = rbv * rbv;
            #pragma unroll
            for (int r = 0; r < RPB; ++r) {
                bf[r] = min(bf[r], rf2 + ds[r]);
                bb[r] = min(bb[r], rb2 + ds[r]);
            }
        }
    }

    // ---- loss math (identical per-pixel ops/order to the verified kernel) ----
    const float MAXD2 = (float)((H - 1) * (H - 1) + (W - 1) * (W - 1));
    float v5[RPB][5];
    #pragma unroll
    for (int r = 0; r < RPB; ++r) {
        const float Df = (bf[r] > EMPTY_THRESH) ? MAXD2 : (float)bf[r];
        const float Db = (bb[r] > EMPTY_THRESH) ? MAXD2 : (float)bb[r];
        const float x  = xv[r];
        const float t  = tv[r];
        const float p   = 1.0f / (1.0f + expf(-x));
        const float phi = (t > 0.5f) ? -sqrtf(Db) : sqrtf(Df);
        const float pc  = fminf(fmaxf(p, FEPS), 1.0f - FEPS);
        const float pt  = pc * t + (1.0f - pc) * (1.0f - t);
        const float at  = 0.25f * t + 0.75f * (1.0f - t);
        const float om  = 1.0f - pt;
        const float fo  = -at * om * om * logf(pt);
        v5[r][0] = p * t; v5[r][1] = p; v5[r][2] = t; v5[r][3] = phi * p; v5[r][4] = fo;
    }

    // ---- per-row block reductions (same tree as before -> bitwise-identical parts) ----
    #pragma unroll
    for (int q = 0; q < 5; ++q) {
        float a0 = v5[0][q], a1 = v5[1][q], a2 = v5[2][q], a3 = v5[3][q];
        #pragma unroll
        for (int off = 32; off > 0; off >>= 1) {
            a0 += __shfl_down(a0, off, 64);
            a1 += __shfl_down(a1, off, 64);
            a2 += __shfl_down(a2, off, 64);
            a3 += __shfl_down(a3, off, 64);
        }
        v5[0][q] = a0; v5[1][q] = a1; v5[2][q] = a2; v5[3][q] = a3;
    }
    if (lane == 0) {
        #pragma unroll
        for (int r = 0; r < RPB; ++r) {
            #pragma unroll
            for (int q = 0; q < 5; ++q) smem[r][wid * 5 + q] = v5[r][q];
        }
    }
    __syncthreads();
    if (px == 0) {
        // publish parts with RELAXED agent-scope stores (no L2 writeback/invalidate),
        // then order the flag store behind them with a bare vmcnt wait.
        #pragma unroll
        for (int r = 0; r < RPB; ++r) {
            #pragma unroll
            for (int q = 0; q < 5; ++q) {
                const float v = smem[r][q] + smem[r][5 + q] + smem[r][10 + q] + smem[r][15 + q];
                __hip_atomic_store(&parts[q * NROW + blk * RPB + r], v,
                                   __ATOMIC_RELAXED, __HIP_MEMORY_SCOPE_AGENT);
            }
        }
        asm volatile("s_waitcnt vmcnt(0)" ::: "memory");
        __hip_atomic_store(&flags[blk], MAGIC, __ATOMIC_RELAXED, __HIP_MEMORY_SCOPE_AGENT);
    }

    // ---- block 0: wait for all producers, then finalize (identical reduction) ----
    if (blk == 0) {
        const int tid = px;
        bool done = false;
        int guard = 0;
        do {
            bool mine = true;
            #pragma unroll
            for (int k = 0; k < NBLK / 256; ++k) {
                const unsigned long long v = __hip_atomic_load(
                    &flags[tid + k * 256], __ATOMIC_RELAXED, __HIP_MEMORY_SCOPE_AGENT);
                mine = mine && (v == MAGIC);
            }
            done = (__syncthreads_and((int)mine) != 0);
            if (!done) __builtin_amdgcn_s_sleep(2);
        } while (!done && (++guard < (1 << 26)));

        // boundary + focal: global sums over all NROW partials
        float bp = 0.0f, fc = 0.0f;
        for (int k = tid; k < NROW; k += 256) {
            bp += __hip_atomic_load(&parts[3 * NROW + k], __ATOMIC_RELAXED, __HIP_MEMORY_SCOPE_AGENT);
            fc += __hip_atomic_load(&parts[4 * NROW + k], __ATOMIC_RELAXED, __HIP_MEMORY_SCOPE_AGENT);
        }
        #pragma unroll
        for (int off = 32; off > 0; off >>= 1) {
            bp += __shfl_down(bp, off, 64);
            fc += __shfl_down(fc, off, 64);
        }
        if (lane == 0) { smf[wid * 2] = bp; smf[wid * 2 + 1] = fc; }

        // dice: each wave handles 2 images (256 partials each)
        #pragma unroll
        for (int mi = 0; mi < 2; ++mi) {
            const int m = wid * 2 + mi;
            float A = 0.f, S = 0.f, C = 0.f;
            #pragma unroll
            for (int k = 0; k < 4; ++k) {
                const int i = m * 256 + k * 64 + lane;
                A += __hip_atomic_load(&parts[0 * NROW + i], __ATOMIC_RELAXED, __HIP_MEMORY_SCOPE_AGENT);
                S += __hip_atomic_load(&parts[1 * NROW + i], __ATOMIC_RELAXED, __HIP_MEMORY_SCOPE_AGENT);
                C += __hip_atomic_load(&parts[2 * NROW + i], __ATOMIC_RELAXED, __HIP_MEMORY_SCOPE_AGENT);
            }
            #pragma unroll
            for (int off = 32; off > 0; off >>= 1) {
                A += __shfl_down(A, off, 64);
                S += __shfl_down(S, off, 64);
                C += __shfl_down(C, off, 64);
            }
            if (lane == 0) sratio[m] = (2.0f * A + FEPS) / (S + C + FEPS);
        }
        __syncthreads();
        if (tid == 0) {
            const float B = smf[0] + smf[2] + smf[4] + smf[6];
            const float F = smf[1] + smf[3] + smf[5] + smf[7];
            float dacc = 0.0f;
            #pragma unroll
            for (int m = 0; m < 8; ++m) dacc += sratio[m];
            const float dice_val     = 1.0f - dacc / (float)N;
            const float boundary_val = B / (float)NPIX;
            const float focal_val    = F / (float)NPIX;
            out[0] = dice_val + boundary_val + focal_val;   // loss
            out[1] = dice_val;
            out[2] = boundary_val;
            out[3] = focal_val;
        }
    }
}

extern "C" void kernel_launch(void* const* d_in, const int* in_sizes, int n_in,
                              void* d_out, int out_size, void* d_ws, size_t ws_size,
                              hipStream_t stream)
{
    const float* pred = (const float*)d_in[0];
    const float* tgt  = (const float*)d_in[1];
    float* out = (float*)d_out;

    float* parts = (float*)d_ws;                                        // 40 KB
    unsigned long long* flags =
        (unsigned long long*)((char*)d_ws + (size_t)5 * NROW * sizeof(float)); // 4 KB

    fused_kernel<<<NBLK, 256, 0, stream>>>(pred, tgt, parts, flags, out);
}

// Round 5
// 67.827 us; speedup vs baseline: 1.0083x; 1.0083x over previous
//
#include <hip/hip_runtime.h>
#include <math.h>
#include <limits.h>

// Problem constants (fixed by reference setup_inputs)
constexpr int N = 8;
constexpr int H = 256;
constexpr int W = 256;
constexpr int NPIX = N * H * W;            // 524288
constexpr float FEPS = 1e-6f;
constexpr int   RSENT = 20000;             // row-empty sentinel: RSENT^2=4e8 >> legit max 130050
constexpr int   EMPTY_THRESH = 300000000;  // > legit max 130050, < RSENT^2
constexpr int   NROW = N * H;              // 2048 per-row partial slots (layout == old kernel)
constexpr int   NBLK = NROW / 2;           // 1024 fused blocks, 2 output rows each
constexpr int   BIGD = 1 << 20;
constexpr unsigned long long MAGIC = 0x9E3779B97F4A7C15ull; // halves differ -> no uniform
                                                            // poison pattern can match

// ws layout:
//   float parts[5][NROW]  : q=0: p*t, 1: p, 2: t, 3: phi*p, 4: focal   (40 KB)
//   u64   flags[NBLK]     : per-block completion magic                  (8 KB)

// ---- nearest-set-bit distances from a 256-bit row mask ----
// Row pixel i <-> bit (i&63) of word (i>>6). Masks are wave-uniform (from __ballot).
// Computes r[k] = distance from pixel p = 64k+lane to nearest set bit (RSENT if none).
__device__ __forceinline__ void mask_dists(
    const unsigned long long m0, const unsigned long long m1,
    const unsigned long long m2, const unsigned long long m3,
    const int lane, int r[4])
{
    // right-chains: dJ = dist from bit0 of word J to nearest set bit in words J..3
    const int f1 = __ffsll((long long)m1), f2 = __ffsll((long long)m2), f3 = __ffsll((long long)m3);
    const int d3 = f3 ? f3 - 1 : BIGD;
    const int d2 = f2 ? f2 - 1 : 64 + d3;
    const int d1 = f1 ? f1 - 1 : 64 + d2;
    // left-chains: eJ = dist from bit63 of word J to nearest set bit in words J..0
    const int c0 = __clzll((long long)m0), c1 = __clzll((long long)m1), c2 = __clzll((long long)m2);
    const int e0 = (c0 < 64) ? c0 : BIGD;
    const int e1 = (c1 < 64) ? c1 : 64 + e0;
    const int e2 = (c2 < 64) ? c2 : 64 + e1;

    const unsigned long long mw[4] = {m0, m1, m2, m3};
    const int dnx[4] = {d1, d2, d3, BIGD};
    const int epv[4] = {BIGD, e0, e1, e2};
    #pragma unroll
    for (int k = 0; k < 4; ++k) {
        const unsigned long long x = mw[k] >> lane;          // bit0 = self
        const int fx = __ffsll((long long)x);
        const int dR = fx ? fx - 1 : (64 - lane) + dnx[k];
        const unsigned long long y = mw[k] << (63 - lane);   // bit63 = self
        const int cy = __clzll((long long)y);
        const int dL = (cy < 64) ? cy : (lane + 1) + epv[k];
        int rr = min(dL, dR);
        if (rr > 255) rr = RSENT;
        r[k] = rr;
    }
}

__global__ __launch_bounds__(256, 4) void fused_kernel(
    const float* __restrict__ pred, const float* __restrict__ tgt,
    float* __restrict__ parts, unsigned long long* __restrict__ flags,
    float* __restrict__ out)
{
    const int blk  = blockIdx.x;            // n*128 + (py>>1)
    const int n    = blk >> 7;
    const int py0  = (blk & 127) << 1;
    const int py1  = py0 + 1;
    const int px   = threadIdx.x;
    const int lane = px & 63;
    const int wid  = px >> 6;

    __shared__ unsigned int rows[8][W];     // packed rf | rb<<16, slot s <-> qy = py0-3+s
    __shared__ float smem[2][20];
    __shared__ float smf[8];
    __shared__ float sratio[8];

    const float* __restrict__ timg = tgt  + (size_t)n * (H * W);
    const float* __restrict__ pimg = pred + (size_t)n * (H * W);

    // ---- window row-scans: wave w computes slots w and w+4 entirely in-wave ----
    #pragma unroll
    for (int sh = 0; sh < 2; ++sh) {
        const int s  = wid + sh * 4;
        const int qy = py0 - 3 + s;
        if (qy >= 0 && qy < H) {            // wave-uniform
            const float a0 = timg[qy * W + lane];
            const float a1 = timg[qy * W + 64 + lane];
            const float a2 = timg[qy * W + 128 + lane];
            const float a3 = timg[qy * W + 192 + lane];
            const unsigned long long m0 = __ballot(a0 > 0.5f);
            const unsigned long long m1 = __ballot(a1 > 0.5f);
            const unsigned long long m2 = __ballot(a2 > 0.5f);
            const unsigned long long m3 = __ballot(a3 > 0.5f);
            int rf[4], rb[4];
            mask_dists(m0, m1, m2, m3, lane, rf);
            mask_dists(~m0, ~m1, ~m2, ~m3, lane, rb);
            #pragma unroll
            for (int k = 0; k < 4; ++k)
                rows[s][(k << 6) + lane] = (unsigned)rf[k] | ((unsigned)rb[k] << 16);
        }
    }

    // hot loads for the loss phase (issue early, overlap with barrier + window min)
    const float x0 = pimg[py0 * W + px];
    const float x1 = pimg[py1 * W + px];
    const float t0 = timg[py0 * W + px];
    const float t1 = timg[py1 * W + px];

    __syncthreads();

    // ---- windowed column pass for both output rows from LDS ----
    int bf0 = INT_MAX, bb0 = INT_MAX, bf1 = INT_MAX, bb1 = INT_MAX;
    #pragma unroll
    for (int s = 0; s < 8; ++s) {
        const int qy = py0 - 3 + s;
        if (qy >= 0 && qy < H) {            // wave-uniform
            const unsigned v = rows[s][px];
            const int rfv = (int)(v & 0xffffu);
            const int rbv = (int)(v >> 16);
            const int rf2 = rfv * rfv, rb2 = rbv * rbv;
            const int d0 = s - 3, d1v = s - 4;
            bf0 = min(bf0, rf2 + d0 * d0);  bb0 = min(bb0, rb2 + d0 * d0);
            bf1 = min(bf1, rf2 + d1v * d1v); bb1 = min(bb1, rb2 + d1v * d1v);
        }
    }

    // ---- rare exact fallback: extend outward, recomputing rows on demand ----
    // Each wave loads the full row, ballots (identical masks), and every thread
    // computes its own pixel's distance: word index = wid (wave-uniform), bit = lane.
    for (int dir = 0; dir < 2; ++dir) {
        const int qy_start = dir ? py0 + 5 : py0 - 4;
        const int qy_step  = dir ? 1 : -1;
        for (int qy = qy_start; qy >= 0 && qy < H; qy += qy_step) {
            const int dd = dir ? (qy - py0) : (py0 - qy);
            const int du1 = dir ? (dd - 1) : (dd + 1);
            const int d0s = dd * dd, d1s = du1 * du1;
            if (!__any((d0s < bf0) | (d0s < bb0) | (d1s < bf1) | (d1s < bb1))) break;
            const float a0 = timg[qy * W + lane];
            const float a1 = timg[qy * W + 64 + lane];
            const float a2 = timg[qy * W + 128 + lane];
            const float a3 = timg[qy * W + 192 + lane];
            const unsigned long long m0 = __ballot(a0 > 0.5f);
            const unsigned long long m1 = __ballot(a1 > 0.5f);
            const unsigned long long m2 = __ballot(a2 > 0.5f);
            const unsigned long long m3 = __ballot(a3 > 0.5f);
            // chains for fg and bg
            int rfv, rbv;
            {
                const int f1 = __ffsll((long long)m1), f2 = __ffsll((long long)m2), f3 = __ffsll((long long)m3);
                const int d3 = f3 ? f3 - 1 : BIGD;
                const int d2 = f2 ? f2 - 1 : 64 + d3;
                const int d1c = f1 ? f1 - 1 : 64 + d2;
                const int c0 = __clzll((long long)m0), c1 = __clzll((long long)m1), c2 = __clzll((long long)m2);
                const int e0 = (c0 < 64) ? c0 : BIGD;
                const int e1 = (c1 < 64) ? c1 : 64 + e0;
                const int e2 = (c2 < 64) ? c2 : 64 + e1;
                const unsigned long long mw = (wid == 0) ? m0 : (wid == 1) ? m1 : (wid == 2) ? m2 : m3;
                const int dnx = (wid == 0) ? d1c : (wid == 1) ? d2 : (wid == 2) ? d3 : BIGD;
                const int epv = (wid == 0) ? BIGD : (wid == 1) ? e0 : (wid == 2) ? e1 : e2;
                const unsigned long long x = mw >> lane;
                const int fx = __ffsll((long long)x);
                const int dR = fx ? fx - 1 : (64 - lane) + dnx;
                const unsigned long long y = mw << (63 - lane);
                const int cy = __clzll((long long)y);
                const int dL = (cy < 64) ? cy : (lane + 1) + epv;
                int rr = min(dL, dR); if (rr > 255) rr = RSENT;
                rfv = rr;
            }
            {
                const unsigned long long b0 = ~m0, b1 = ~m1, b2 = ~m2, b3 = ~m3;
                const int f1 = __ffsll((long long)b1), f2 = __ffsll((long long)b2), f3 = __ffsll((long long)b3);
                const int d3 = f3 ? f3 - 1 : BIGD;
                const int d2 = f2 ? f2 - 1 : 64 + d3;
                const int d1c = f1 ? f1 - 1 : 64 + d2;
                const int c0 = __clzll((long long)b0), c1 = __clzll((long long)b1), c2 = __clzll((long long)b2);
                const int e0 = (c0 < 64) ? c0 : BIGD;
                const int e1 = (c1 < 64) ? c1 : 64 + e0;
                const int e2 = (c2 < 64) ? c2 : 64 + e1;
                const unsigned long long mw = (wid == 0) ? b0 : (wid == 1) ? b1 : (wid == 2) ? b2 : b3;
                const int dnx = (wid == 0) ? d1c : (wid == 1) ? d2 : (wid == 2) ? d3 : BIGD;
                const int epv = (wid == 0) ? BIGD : (wid == 1) ? e0 : (wid == 2) ? e1 : e2;
                const unsigned long long x = mw >> lane;
                const int fx = __ffsll((long long)x);
                const int dR = fx ? fx - 1 : (64 - lane) + dnx;
                const unsigned long long y = mw << (63 - lane);
                const int cy = __clzll((long long)y);
                const int dL = (cy < 64) ? cy : (lane + 1) + epv;
                int rr = min(dL, dR); if (rr > 255) rr = RSENT;
                rbv = rr;
            }
            const int rf2 = rfv * rfv, rb2 = rbv * rbv;
            bf0 = min(bf0, rf2 + d0s); bb0 = min(bb0, rb2 + d0s);
            bf1 = min(bf1, rf2 + d1s); bb1 = min(bb1, rb2 + d1s);
        }
    }

    // ---- loss math (identical ops/order to the verified kernel) ----
    const float MAXD2 = (float)((H - 1) * (H - 1) + (W - 1) * (W - 1));
    const float Df0 = (bf0 > EMPTY_THRESH) ? MAXD2 : (float)bf0;
    const float Db0 = (bb0 > EMPTY_THRESH) ? MAXD2 : (float)bb0;
    const float Df1 = (bf1 > EMPTY_THRESH) ? MAXD2 : (float)bf1;
    const float Db1 = (bb1 > EMPTY_THRESH) ? MAXD2 : (float)bb1;

    const float p0   = 1.0f / (1.0f + expf(-x0));
    const float phi0 = (t0 > 0.5f) ? -sqrtf(Db0) : sqrtf(Df0);
    const float pc0  = fminf(fmaxf(p0, FEPS), 1.0f - FEPS);
    const float pt0  = pc0 * t0 + (1.0f - pc0) * (1.0f - t0);
    const float at0  = 0.25f * t0 + 0.75f * (1.0f - t0);
    const float om0  = 1.0f - pt0;
    const float fo0  = -at0 * om0 * om0 * logf(pt0);

    const float p1   = 1.0f / (1.0f + expf(-x1));
    const float phi1 = (t1 > 0.5f) ? -sqrtf(Db1) : sqrtf(Df1);
    const float pc1  = fminf(fmaxf(p1, FEPS), 1.0f - FEPS);
    const float pt1  = pc1 * t1 + (1.0f - pc1) * (1.0f - t1);
    const float at1  = 0.25f * t1 + 0.75f * (1.0f - t1);
    const float om1  = 1.0f - pt1;
    const float fo1  = -at1 * om1 * om1 * logf(pt1);

    // ---- per-row block reductions (same tree as before -> bitwise-identical parts) ----
    float v50[5] = { p0 * t0, p0, t0, phi0 * p0, fo0 };
    float v51[5] = { p1 * t1, p1, t1, phi1 * p1, fo1 };
    #pragma unroll
    for (int q = 0; q < 5; ++q) {
        float a = v50[q], b = v51[q];
        #pragma unroll
        for (int off = 32; off > 0; off >>= 1) {
            a += __shfl_down(a, off, 64);
            b += __shfl_down(b, off, 64);
        }
        v50[q] = a; v51[q] = b;
    }
    if (lane == 0) {
        #pragma unroll
        for (int q = 0; q < 5; ++q) {
            smem[0][wid * 5 + q] = v50[q];
            smem[1][wid * 5 + q] = v51[q];
        }
    }
    __syncthreads();
    if (px == 0) {
        // publish parts with RELAXED agent-scope stores (no L2 writeback/invalidate),
        // then order the flag store behind them with a bare vmcnt wait.
        #pragma unroll
        for (int r = 0; r < 2; ++r) {
            #pragma unroll
            for (int q = 0; q < 5; ++q) {
                const float v = smem[r][q] + smem[r][5 + q] + smem[r][10 + q] + smem[r][15 + q];
                __hip_atomic_store(&parts[q * NROW + blk * 2 + r], v,
                                   __ATOMIC_RELAXED, __HIP_MEMORY_SCOPE_AGENT);
            }
        }
        asm volatile("s_waitcnt vmcnt(0)" ::: "memory");
        __hip_atomic_store(&flags[blk], MAGIC, __ATOMIC_RELAXED, __HIP_MEMORY_SCOPE_AGENT);
    }

    // ---- block 0: wait for all producers, then finalize (identical reduction) ----
    if (blk == 0) {
        const int tid = px;
        bool done = false;
        int guard = 0;
        do {
            bool mine = true;
            #pragma unroll
            for (int k = 0; k < NBLK / 256; ++k) {
                const unsigned long long v = __hip_atomic_load(
                    &flags[tid + k * 256], __ATOMIC_RELAXED, __HIP_MEMORY_SCOPE_AGENT);
                mine = mine && (v == MAGIC);
            }
            done = (__syncthreads_and((int)mine) != 0);
            if (!done) __builtin_amdgcn_s_sleep(2);
        } while (!done && (++guard < (1 << 26)));

        // boundary + focal: global sums over all NROW partials
        float bp = 0.0f, fc = 0.0f;
        for (int k = tid; k < NROW; k += 256) {
            bp += __hip_atomic_load(&parts[3 * NROW + k], __ATOMIC_RELAXED, __HIP_MEMORY_SCOPE_AGENT);
            fc += __hip_atomic_load(&parts[4 * NROW + k], __ATOMIC_RELAXED, __HIP_MEMORY_SCOPE_AGENT);
        }
        #pragma unroll
        for (int off = 32; off > 0; off >>= 1) {
            bp += __shfl_down(bp, off, 64);
            fc += __shfl_down(fc, off, 64);
        }
        if (lane == 0) { smf[wid * 2] = bp; smf[wid * 2 + 1] = fc; }

        // dice: each wave handles 2 images (256 partials each)
        #pragma unroll
        for (int mi = 0; mi < 2; ++mi) {
            const int m = wid * 2 + mi;
            float A = 0.f, S = 0.f, C = 0.f;
            #pragma unroll
            for (int k = 0; k < 4; ++k) {
                const int i = m * 256 + k * 64 + lane;
                A += __hip_atomic_load(&parts[0 * NROW + i], __ATOMIC_RELAXED, __HIP_MEMORY_SCOPE_AGENT);
                S += __hip_atomic_load(&parts[1 * NROW + i], __ATOMIC_RELAXED, __HIP_MEMORY_SCOPE_AGENT);
                C += __hip_atomic_load(&parts[2 * NROW + i], __ATOMIC_RELAXED, __HIP_MEMORY_SCOPE_AGENT);
            }
            #pragma unroll
            for (int off = 32; off > 0; off >>= 1) {
                A += __shfl_down(A, off, 64);
                S += __shfl_down(S, off, 64);
                C += __shfl_down(C, off, 64);
            }
            if (lane == 0) sratio[m] = (2.0f * A + FEPS) / (S + C + FEPS);
        }
        __syncthreads();
        if (tid == 0) {
            const float B = smf[0] + smf[2] + smf[4] + smf[6];
            const float F = smf[1] + smf[3] + smf[5] + smf[7];
            float dacc = 0.0f;
            #pragma unroll
            for (int m = 0; m < 8; ++m) dacc += sratio[m];
            const float dice_val     = 1.0f - dacc / (float)N;
            const float boundary_val = B / (float)NPIX;
            const float focal_val    = F / (float)NPIX;
            out[0] = dice_val + boundary_val + focal_val;   // loss
            out[1] = dice_val;
            out[2] = boundary_val;
            out[3] = focal_val;
        }
    }
}

extern "C" void kernel_launch(void* const* d_in, const int* in_sizes, int n_in,
                              void* d_out, int out_size, void* d_ws, size_t ws_size,
                              hipStream_t stream)
{
    const float* pred = (const float*)d_in[0];
    const float* tgt  = (const float*)d_in[1];
    float* out = (float*)d_out;

    float* parts = (float*)d_ws;                                        // 40 KB
    unsigned long long* flags =
        (unsigned long long*)((char*)d_ws + (size_t)5 * NROW * sizeof(float)); // 8 KB

    fused_kernel<<<NBLK, 256, 0, stream>>>(pred, tgt, parts, flags, out);
}